// Round 8
// baseline (117.229 us; speedup 1.0000x reference)
//
#include <hip/hip_runtime.h>

#define B_ 32
#define C_ 80
#define T_ 2048
#define W_ 128
#define H_ 512
#define K_ 5

#define KTOT 400          // C_*K_
#define NKI  13           // K iterations of 32
#define TM   128
#define TN   128
#define SF_STRIDE 80      // == C_: makes staging + A addressing exactly linear
#define SF_ROWS   136     // 128 + 4 halo + slack; 136*80 f16 = 21760 B
#define SF_ELEMS  (SF_ROWS * SF_STRIDE)
#define ITER_STRIDE (2 * 4 * 64 * 8)               // Bf elems per K-iter per nt
#define BF_ELEMS  (4 * NKI * ITER_STRIDE)          // [nt][it][w2][j][lane][8] = 212992

// prep_all block-role boundaries
#define RB_FEAT   1024                             // feat transpose blocks
#define RB_BFRAG  (RB_FEAT + BF_ELEMS / 256)       // +832 = 1856
#define RB_WORDS  (RB_BFRAG + B_)                  // +32  = 1888

#define TILE_S 88                                  // 80 + 8 pad: reduces LDS write conflict, keeps 16B f4v alignment

typedef _Float16 half8 __attribute__((ext_vector_type(8)));
typedef float    f4v   __attribute__((ext_vector_type(4)));

typedef const __attribute__((address_space(1))) unsigned int guint;
typedef __attribute__((address_space(3))) unsigned int luint;

// ---------------------------------------------------------------------------
// prep_all: one dispatch, three roles by blockIdx.x (unchanged)
// ---------------------------------------------------------------------------
__global__ __launch_bounds__(256) void prep_all(
    const float* __restrict__ feat, const float* __restrict__ enc_w,
    const int* __restrict__ bounds, const int* __restrict__ lengths,
    _Float16* __restrict__ featT, _Float16* __restrict__ Bf,
    int* __restrict__ word_of, float* __restrict__ inv_cnt)
{
    __shared__ _Float16 tile[64 * TILE_S];
    const int bid = blockIdx.x;
    const int tid = threadIdx.x;

    if (bid < RB_FEAT) {
        const int b = bid >> 5, tc = bid & 31;
        const int t0 = tc * 64;
        for (int idx = tid; idx < 80 * 64; idx += 256) {
            int cc = idx >> 6, tt = idx & 63;                  // coalesced over tt
            float v = feat[((size_t)b * C_ + cc) * T_ + t0 + tt];
            tile[tt * TILE_S + cc] = (_Float16)v;
        }
        __syncthreads();
        for (int idx = tid; idx < 64 * 10; idx += 256) {
            int tt = idx / 10, g = idx % 10;                   // coalesced writes
            *(f4v*)(featT + ((size_t)b * T_ + t0 + tt) * C_ + g * 8) =
                *(const f4v*)(tile + tt * TILE_S + g * 8);
        }
    } else if (bid < RB_BFRAG) {
        int idx = (bid - RB_FEAT) * 256 + tid;                 // < BF_ELEMS exactly
        int e  = idx & 7;
        int l  = (idx >> 3) & 63;
        int j  = (idx >> 9) & 3;
        int w2 = (idx >> 11) & 1;
        int it = (idx >> 12) % NKI;
        int nt = idx / (NKI << 12);
        int h  = nt * 128 + w2 * 64 + j * 16 + (l & 15);
        int kc = it * 32 + (l >> 4) * 8 + e;
        float v = 0.f;
        if (kc < KTOT) v = enc_w[(h * C_ + kc % 80) * K_ + kc / 80];
        Bf[idx] = (_Float16)v;
    } else {
        const int b = bid - RB_BFRAG;
        int* wob = word_of + b * T_;
        for (int t = tid; t < T_; t += 256) wob[t] = -1;
        __syncthreads();
        if (tid < W_) {
            const int len = lengths[b];
            int s = bounds[(b * 2 + 0) * W_ + tid];
            int e = bounds[(b * 2 + 1) * W_ + tid];
            s = max(s, 0); e = min(e, T_);
            bool valid = (tid < len) && (e > s);
            inv_cnt[b * W_ + tid] = valid ? 1.f / (float)(e - s) : 0.f;
            if (valid)
                for (int t = s; t < e; ++t) wob[t] = tid;      // disjoint words
        }
    }
}

// ---------------------------------------------------------------------------
// Implicit-GEMM conv (f16 MFMA) + bias + ReLU + word mean-pool into wemb.
// R8 = R7 with deeper per-wave ILP (the only remaining lever at the
// 129-256 unified-reg occupancy band = 2 waves/SIMD regardless of bounds):
//  - A LDS prefetch 2-deep (it+1, it+2): ~240cyc tolerance vs ~120+cyc
//    contended LDS latency.
//  - B global prefetch 3-deep (unchanged from R7).
//  - launch_bounds(256,2): removes forced-squeeze/spill pressure; real
//    occupancy is band-limited to 2 waves/SIMD either way (m69 steps).
// ---------------------------------------------------------------------------
__global__ __launch_bounds__(256, 2) void gemm_enc(
    const _Float16* __restrict__ featT,   // (B,T,C)
    const _Float16* __restrict__ Bf,      // wave-order fragments (padded +4 iters)
    const float*    __restrict__ enc_b,   // (H)
    const int*      __restrict__ word_of, // (B,T)
    const float*    __restrict__ inv_cnt, // (B,W)
    float*          __restrict__ wemb)    // (B,W,H)
{
    __shared__ __attribute__((aligned(16))) _Float16 sf[SF_ELEMS];   // 21.25 KB

    const int tid = threadIdx.x;
    // bijective XCD co-location remap: all 4 nt of one g=(b,mt) share bid%8
    const int bid = blockIdx.x;                   // 0..2047
    const int xcd = bid & 7;
    const int u   = bid >> 3;                     // 0..255
    const int nt  = u & 3;
    const int g   = xcd + ((u >> 2) << 3);        // 0..511
    const int b   = g >> 4;
    const int mt  = g & 15;
    const int t0 = mt * TM;
    const int h0 = nt * TN;

    const int lane = tid & 63;
    const int wid  = tid >> 6;
    const int wm = (wid >> 1) * 64;
    const int wn = (wid & 1) * 64;
    const int w2 = wid & 1;
    const int ml = lane & 15;
    const int q  = lane >> 4;

    // ---- stage A tile via global_load_lds (16 B/lane, linear both sides) ----
    {
        const _Float16* fb = featT + (size_t)b * T_ * C_;
        const int fbase = (t0 - 2) * C_;                 // may be <0 (mt==0)
        const int gmax  = T_ * C_ - 8;                   // clamp; garbage re-zeroed
        for (int ch = wid; ch < 22; ch += 4) {           // 21 full + 1 tail chunk
            int loff = (ch << 9) + lane * 8;
            if (loff < SF_ELEMS) {                       // tail: lanes >=16 masked
                int goff = fbase + loff;
                goff = min(max(goff, 0), gmax);
                __builtin_amdgcn_global_load_lds((guint*)(fb + goff),
                                                 (luint*)(sf + (ch << 9)), 16, 0, 0);
            }
        }
    }

    // ---- epilogue scalar prefetch (overlaps staging drain) ----
    const int bT = b * T_;
    const int bW = b * W_;
    int wlo[4], whi[4];
    unsigned ownm = 0;
    {
        int wpv[4], wnx[4];
        #pragma unroll
        for (int i = 0; i < 4; ++i) {
            const int tg = t0 + wm + i * 16;
            wlo[i] = word_of[bT + tg];
            whi[i] = word_of[bT + tg + 15];
            wpv[i] = (tg == 0)       ? -2 : word_of[bT + tg - 1];
            wnx[i] = (tg + 16 >= T_) ? -2 : word_of[bT + tg + 16];
        }
        #pragma unroll
        for (int i = 0; i < 4; ++i)
            if (wpv[i] != wlo[i] && wnx[i] != wlo[i]) ownm |= (1u << i);
    }

    // ---- B fragment stream: preload it0/it1/it2 BEFORE the barrier ----
    const half8* bfp = (const half8*)(Bf + (((nt * NKI) * 2 + w2) * 4 * 64 + lane) * 8);
    half8 b0[4], b1[4], b2[4];
    #pragma unroll
    for (int j = 0; j < 4; ++j) b0[j] = bfp[j * 64];
    #pragma unroll
    for (int j = 0; j < 4; ++j) b1[j] = bfp[512 + j * 64];
    #pragma unroll
    for (int j = 0; j < 4; ++j) b2[j] = bfp[1024 + j * 64];

    __syncthreads();   // drains global_load_lds (vmcnt) + barrier

    // SAME-pad rows outside [0,T) hold clamp-garbage in edge blocks: zero them.
    if (mt == 0) {                       // rows 0,1 (t=-2,-1): 160 f16 = 20 f4v
        if (tid < 20) ((f4v*)sf)[tid] = (f4v){};
        __syncthreads();
    }
    if (mt == 15) {                      // rows 130..135 (t>=2048): 60 f4v
        if (tid < 60) ((f4v*)(sf + 130 * SF_STRIDE))[tid] = (f4v){};
        __syncthreads();
    }

    f4v acc[4][4] = {};

    // A addressing is linear: af(it,i) = sf + abase + it*32 + i*16*80
    // max offset: abase(<=6344) + 14*32 + 3*16*80 = 10632 < SF_ELEMS ✓
    const int abase = (wm + ml) * SF_STRIDE + q * 8;

    // preload A(it0), A(it1): 2-deep
    half8 a0[4], a1[4];
    #pragma unroll
    for (int i = 0; i < 4; ++i)
        a0[i] = *(const half8*)(sf + abase + i * 16 * SF_STRIDE);
    #pragma unroll
    for (int i = 0; i < 4; ++i)
        a1[i] = *(const half8*)(sf + abase + 32 + i * 16 * SF_STRIDE);

    #pragma unroll
    for (int it = 0; it < NKI; ++it) {
        half8 a2[4], bnn[4];
        #pragma unroll
        for (int i = 0; i < 4; ++i)      // A(it+2); slack rows cover it+2<=14
            a2[i] = *(const half8*)(sf + abase + (it + 2) * 32 + i * 16 * SF_STRIDE);
        {                                // B(it+3); Bf padded +4 iters (dead loads ok)
            const half8* bn = bfp + (it + 3) * 512;
            #pragma unroll
            for (int j = 0; j < 4; ++j) bnn[j] = bn[j * 64];
        }
        #pragma unroll
        for (int i = 0; i < 4; ++i)
            #pragma unroll
            for (int j = 0; j < 4; ++j)
                acc[i][j] = __builtin_amdgcn_mfma_f32_16x16x32_f16(a0[i], b0[j], acc[i][j], 0, 0, 0);
        #pragma unroll
        for (int i = 0; i < 4; ++i) { a0[i] = a1[i]; a1[i] = a2[i]; }
        #pragma unroll
        for (int j = 0; j < 4; ++j) { b0[j] = b1[j]; b1[j] = b2[j]; b2[j] = bnn[j]; }
    }

    // ---- epilogue: bias + ReLU + mean-pool; coalesced full-row stores ----
    float bias[4], invp[4];
    #pragma unroll
    for (int j = 0; j < 4; ++j) bias[j] = enc_b[h0 + wn + j * 16 + ml];
    #pragma unroll
    for (int i = 0; i < 4; ++i) invp[i] = inv_cnt[bW + max(wlo[i], 0)];

    #pragma unroll
    for (int i = 0; i < 4; ++i) {
        const int tg = t0 + wm + i * 16;
        const int w0  = wlo[i];
        const int w15 = whi[i];
        if (w0 == w15) {
            if (w0 >= 0) {
                const float inv = invp[i];
                const bool own = (ownm >> i) & 1;
                float sj[4];
                #pragma unroll
                for (int j = 0; j < 4; ++j) {
                    float s = 0.f;
                    #pragma unroll
                    for (int r = 0; r < 4; ++r) s += fmaxf(acc[i][j][r] + bias[j], 0.f);
                    s += __shfl_down(s, 32, 64);
                    s += __shfl_down(s, 16, 64);
                    sj[j] = s;                      // full sum valid on lanes 0..15
                }
                // redistribute: lane L holds row value for column wn + L
                float v0 = __shfl(sj[0], ml, 64);
                float v1 = __shfl(sj[1], ml, 64);
                float v2 = __shfl(sj[2], ml, 64);
                float v3 = __shfl(sj[3], ml, 64);
                float vv = (q == 0) ? v0 : (q == 1) ? v1 : (q == 2) ? v2 : v3;
                float val = vv * inv;
                float* dst = &wemb[(size_t)(bW + w0) * H_ + h0 + wn + lane];
                if (own) *dst = val;                // 64 lanes: 256B coalesced
                else atomicAdd(dst, val);
            }
        } else {
            #pragma unroll
            for (int j = 0; j < 4; ++j) {
                #pragma unroll
                for (int r = 0; r < 4; ++r) {
                    int t = tg + q * 4 + r;
                    int w = word_of[bT + t];
                    if (w >= 0)
                        atomicAdd(&wemb[(size_t)(bW + w) * H_ + h0 + wn + j * 16 + ml],
                                  fmaxf(acc[i][j][r] + bias[j], 0.f) * inv_cnt[bW + w]);
                }
            }
        }
    }
}

// ---------------------------------------------------------------------------
// Decoder: 512 blocks (b x 16 chunks of 8 words) for latency-hiding
// ---------------------------------------------------------------------------
__global__ __launch_bounds__(256) void dec_all(const float* __restrict__ wemb,
                                               const float* __restrict__ dec_w,
                                               const float* __restrict__ dec_b,
                                               float* __restrict__ out) {
    __shared__ float sdw[H_ * K_];       // 10.2 KB
    __shared__ float se[16][8];          // 12 rows used, k-stride 8
    const int bid = blockIdx.x;          // b*16 + ch
    const int b = bid >> 4, ch = bid & 15;
    const int w0 = ch * 8;
    for (int idx = threadIdx.x; idx < H_ * K_; idx += 256) sdw[idx] = dec_w[idx];
    __syncthreads();
    const int wid = threadIdx.x >> 6, lane = threadIdx.x & 63;
    for (int row = wid; row < 12; row += 4) {
        int wq = w0 - 2 + row;
        float a[K_] = {};
        if (wq >= 0 && wq < W_) {
            const float* src = wemb + ((size_t)b * W_ + wq) * H_;
            #pragma unroll
            for (int r = 0; r < H_ / 64; ++r) {
                int h = r * 64 + lane;
                float v = src[h];
                #pragma unroll
                for (int k = 0; k < K_; ++k) a[k] += v * sdw[h * K_ + k];
            }
        }
        #pragma unroll
        for (int k = 0; k < K_; ++k) {
            #pragma unroll
            for (int off = 32; off > 0; off >>= 1) a[k] += __shfl_down(a[k], off, 64);
        }
        if (lane == 0) {
            #pragma unroll
            for (int k = 0; k < K_; ++k) se[row][k] = a[k];
        }
    }
    __syncthreads();
    if (threadIdx.x < 8) {
        int wl = threadIdx.x;
        float acc = dec_b[0];
        #pragma unroll
        for (int k = 0; k < K_; ++k) acc += se[wl + k][k];
        out[b * W_ + w0 + wl] = acc;
    }
}

// ---------------------------------------------------------------------------
extern "C" void kernel_launch(void* const* d_in, const int* in_sizes, int n_in,
                              void* d_out, int out_size, void* d_ws, size_t ws_size,
                              hipStream_t stream) {
    const float* feat    = (const float*)d_in[0];
    const int*   bounds  = (const int*)  d_in[1];
    const int*   lengths = (const int*)  d_in[2];
    const float* enc_w   = (const float*)d_in[3];
    const float* enc_b   = (const float*)d_in[4];
    const float* dec_w   = (const float*)d_in[5];
    const float* dec_b   = (const float*)d_in[6];
    float* out = (float*)d_out;

    char* p = (char*)d_ws;
    _Float16* featT = (_Float16*)p;  p += (size_t)B_ * T_ * C_ * 2;                 // 10.49 MB
    _Float16* Bf    = (_Float16*)p;  p += (size_t)(BF_ELEMS + 4 * ITER_STRIDE) * 2; // 0.44 MB (+4-iter pad)
    int* word_of    = (int*)p;       p += (size_t)B_ * T_ * 4;                      // 0.26 MB
    float* inv_cnt  = (float*)p;     p += (size_t)B_ * W_ * 4;                      // 16 KB
    float* wemb     = (float*)p;                                                    // 8.39 MB (no pre-zero needed)

    prep_all<<<RB_WORDS, 256, 0, stream>>>(feat, enc_w, bounds, lengths,
                                           featT, Bf, word_of, inv_cnt);
    gemm_enc<<<B_ * (T_ / TM) * (H_ / TN), 256, 0, stream>>>(
        featT, Bf, enc_b, word_of, inv_cnt, wemb);
    dec_all<<<B_ * 16, 256, 0, stream>>>(wemb, dec_w, dec_b, out);
}

// Round 9
// 115.798 us; speedup vs baseline: 1.0124x; 1.0124x over previous
//
#include <hip/hip_runtime.h>

#define B_ 32
#define C_ 80
#define T_ 2048
#define W_ 128
#define H_ 512
#define K_ 5

#define KTOT 400          // C_*K_
#define NKI  13           // K iterations of 32
#define TM   128
#define TN   128
#define SF_STRIDE 80      // == C_: makes staging + A addressing exactly linear
#define SF_ROWS   136     // 128 + 4 halo + slack; 136*80 f16 = 21760 B
#define SF_ELEMS  (SF_ROWS * SF_STRIDE)
#define ITER_STRIDE (2 * 4 * 64 * 8)               // Bf elems per K-iter per nt
#define BF_ELEMS  (4 * NKI * ITER_STRIDE)          // [nt][it][w2][j][lane][8] = 212992

// prep_all block-role boundaries
#define RB_FEAT   1024                             // feat transpose blocks
#define RB_BFRAG  (RB_FEAT + BF_ELEMS / 256)       // +832 = 1856
#define RB_WORDS  (RB_BFRAG + B_)                  // +32  = 1888

#define TILE_S 88                                  // 80 + 8 pad: reduces LDS write conflict, keeps 16B f4v alignment

typedef _Float16 half8 __attribute__((ext_vector_type(8)));
typedef float    f4v   __attribute__((ext_vector_type(4)));

typedef const __attribute__((address_space(1))) unsigned int guint;
typedef __attribute__((address_space(3))) unsigned int luint;

// ---------------------------------------------------------------------------
// prep_all: one dispatch, three roles by blockIdx.x (unchanged)
// ---------------------------------------------------------------------------
__global__ __launch_bounds__(256) void prep_all(
    const float* __restrict__ feat, const float* __restrict__ enc_w,
    const int* __restrict__ bounds, const int* __restrict__ lengths,
    _Float16* __restrict__ featT, _Float16* __restrict__ Bf,
    int* __restrict__ word_of, float* __restrict__ inv_cnt)
{
    __shared__ _Float16 tile[64 * TILE_S];
    const int bid = blockIdx.x;
    const int tid = threadIdx.x;

    if (bid < RB_FEAT) {
        const int b = bid >> 5, tc = bid & 31;
        const int t0 = tc * 64;
        for (int idx = tid; idx < 80 * 64; idx += 256) {
            int cc = idx >> 6, tt = idx & 63;                  // coalesced over tt
            float v = feat[((size_t)b * C_ + cc) * T_ + t0 + tt];
            tile[tt * TILE_S + cc] = (_Float16)v;
        }
        __syncthreads();
        for (int idx = tid; idx < 64 * 10; idx += 256) {
            int tt = idx / 10, g = idx % 10;                   // coalesced writes
            *(f4v*)(featT + ((size_t)b * T_ + t0 + tt) * C_ + g * 8) =
                *(const f4v*)(tile + tt * TILE_S + g * 8);
        }
    } else if (bid < RB_BFRAG) {
        int idx = (bid - RB_FEAT) * 256 + tid;                 // < BF_ELEMS exactly
        int e  = idx & 7;
        int l  = (idx >> 3) & 63;
        int j  = (idx >> 9) & 3;
        int w2 = (idx >> 11) & 1;
        int it = (idx >> 12) % NKI;
        int nt = idx / (NKI << 12);
        int h  = nt * 128 + w2 * 64 + j * 16 + (l & 15);
        int kc = it * 32 + (l >> 4) * 8 + e;
        float v = 0.f;
        if (kc < KTOT) v = enc_w[(h * C_ + kc % 80) * K_ + kc / 80];
        Bf[idx] = (_Float16)v;
    } else {
        const int b = bid - RB_BFRAG;
        int* wob = word_of + b * T_;
        for (int t = tid; t < T_; t += 256) wob[t] = -1;
        __syncthreads();
        if (tid < W_) {
            const int len = lengths[b];
            int s = bounds[(b * 2 + 0) * W_ + tid];
            int e = bounds[(b * 2 + 1) * W_ + tid];
            s = max(s, 0); e = min(e, T_);
            bool valid = (tid < len) && (e > s);
            inv_cnt[b * W_ + tid] = valid ? 1.f / (float)(e - s) : 0.f;
            if (valid)
                for (int t = s; t < e; ++t) wob[t] = tid;      // disjoint words
        }
    }
}

// ---------------------------------------------------------------------------
// Implicit-GEMM conv (f16 MFMA) + bias + ReLU + word mean-pool into wemb.
// R9 = R7 exact revert (best measured: 115.47 us).
//  - TM=128, acc[4][4], LDS A-stage via global_load_lds, XCD co-location,
//    hoisted epilogue scalars, B global prefetch 3-deep, A prefetch 1-deep,
//    coalesced full-row epilogue stores.
// ---------------------------------------------------------------------------
__global__ __launch_bounds__(256, 3) void gemm_enc(
    const _Float16* __restrict__ featT,   // (B,T,C)
    const _Float16* __restrict__ Bf,      // wave-order fragments (padded +4 iters)
    const float*    __restrict__ enc_b,   // (H)
    const int*      __restrict__ word_of, // (B,T)
    const float*    __restrict__ inv_cnt, // (B,W)
    float*          __restrict__ wemb)    // (B,W,H)
{
    __shared__ __attribute__((aligned(16))) _Float16 sf[SF_ELEMS];   // 21.25 KB

    const int tid = threadIdx.x;
    // bijective XCD co-location remap: all 4 nt of one g=(b,mt) share bid%8
    const int bid = blockIdx.x;                   // 0..2047
    const int xcd = bid & 7;
    const int u   = bid >> 3;                     // 0..255
    const int nt  = u & 3;
    const int g   = xcd + ((u >> 2) << 3);        // 0..511
    const int b   = g >> 4;
    const int mt  = g & 15;
    const int t0 = mt * TM;
    const int h0 = nt * TN;

    const int lane = tid & 63;
    const int wid  = tid >> 6;
    const int wm = (wid >> 1) * 64;
    const int wn = (wid & 1) * 64;
    const int w2 = wid & 1;
    const int ml = lane & 15;
    const int q  = lane >> 4;

    // ---- stage A tile via global_load_lds (16 B/lane, linear both sides) ----
    {
        const _Float16* fb = featT + (size_t)b * T_ * C_;
        const int fbase = (t0 - 2) * C_;                 // may be <0 (mt==0)
        const int gmax  = T_ * C_ - 8;                   // clamp; garbage re-zeroed
        for (int ch = wid; ch < 22; ch += 4) {           // 21 full + 1 tail chunk
            int loff = (ch << 9) + lane * 8;
            if (loff < SF_ELEMS) {                       // tail: lanes >=16 masked
                int goff = fbase + loff;
                goff = min(max(goff, 0), gmax);
                __builtin_amdgcn_global_load_lds((guint*)(fb + goff),
                                                 (luint*)(sf + (ch << 9)), 16, 0, 0);
            }
        }
    }

    // ---- epilogue scalar prefetch (overlaps staging drain) ----
    const int bT = b * T_;
    const int bW = b * W_;
    int wlo[4], whi[4];
    unsigned ownm = 0;
    {
        int wpv[4], wnx[4];
        #pragma unroll
        for (int i = 0; i < 4; ++i) {
            const int tg = t0 + wm + i * 16;
            wlo[i] = word_of[bT + tg];
            whi[i] = word_of[bT + tg + 15];
            wpv[i] = (tg == 0)       ? -2 : word_of[bT + tg - 1];
            wnx[i] = (tg + 16 >= T_) ? -2 : word_of[bT + tg + 16];
        }
        #pragma unroll
        for (int i = 0; i < 4; ++i)
            if (wpv[i] != wlo[i] && wnx[i] != wlo[i]) ownm |= (1u << i);
    }

    // ---- B fragment stream: preload it0/it1/it2 BEFORE the barrier ----
    const half8* bfp = (const half8*)(Bf + (((nt * NKI) * 2 + w2) * 4 * 64 + lane) * 8);
    half8 b0[4], b1[4], b2[4];
    #pragma unroll
    for (int j = 0; j < 4; ++j) b0[j] = bfp[j * 64];
    #pragma unroll
    for (int j = 0; j < 4; ++j) b1[j] = bfp[512 + j * 64];
    #pragma unroll
    for (int j = 0; j < 4; ++j) b2[j] = bfp[1024 + j * 64];

    __syncthreads();   // drains global_load_lds (vmcnt) + barrier

    // SAME-pad rows outside [0,T) hold clamp-garbage in edge blocks: zero them.
    if (mt == 0) {                       // rows 0,1 (t=-2,-1): 160 f16 = 20 f4v
        if (tid < 20) ((f4v*)sf)[tid] = (f4v){};
        __syncthreads();
    }
    if (mt == 15) {                      // rows 130..135 (t>=2048): 60 f4v
        if (tid < 60) ((f4v*)(sf + 130 * SF_STRIDE))[tid] = (f4v){};
        __syncthreads();
    }

    f4v acc[4][4] = {};

    // A addressing is linear: af(it,i) = sf + abase + it*32 + i*16*80
    const int abase = (wm + ml) * SF_STRIDE + q * 8;

    // preload A(it0)
    half8 acur[4];
    #pragma unroll
    for (int i = 0; i < 4; ++i)
        acur[i] = *(const half8*)(sf + abase + i * 16 * SF_STRIDE);

    #pragma unroll
    for (int it = 0; it < NKI; ++it) {
        half8 anxt[4], bnn[4];
        #pragma unroll
        for (int i = 0; i < 4; ++i)      // A(it+1); max offset < SF_ELEMS (slack)
            anxt[i] = *(const half8*)(sf + abase + (it + 1) * 32 + i * 16 * SF_STRIDE);
        {                                // B(it+3); Bf padded +4 iters (dead loads ok)
            const half8* bn = bfp + (it + 3) * 512;
            #pragma unroll
            for (int j = 0; j < 4; ++j) bnn[j] = bn[j * 64];
        }
        #pragma unroll
        for (int i = 0; i < 4; ++i)
            #pragma unroll
            for (int j = 0; j < 4; ++j)
                acc[i][j] = __builtin_amdgcn_mfma_f32_16x16x32_f16(acur[i], b0[j], acc[i][j], 0, 0, 0);
        #pragma unroll
        for (int i = 0; i < 4; ++i) acur[i] = anxt[i];
        #pragma unroll
        for (int j = 0; j < 4; ++j) { b0[j] = b1[j]; b1[j] = b2[j]; b2[j] = bnn[j]; }
    }

    // ---- epilogue: bias + ReLU + mean-pool; coalesced full-row stores ----
    float bias[4], invp[4];
    #pragma unroll
    for (int j = 0; j < 4; ++j) bias[j] = enc_b[h0 + wn + j * 16 + ml];
    #pragma unroll
    for (int i = 0; i < 4; ++i) invp[i] = inv_cnt[bW + max(wlo[i], 0)];

    #pragma unroll
    for (int i = 0; i < 4; ++i) {
        const int tg = t0 + wm + i * 16;
        const int w0  = wlo[i];
        const int w15 = whi[i];
        if (w0 == w15) {
            if (w0 >= 0) {
                const float inv = invp[i];
                const bool own = (ownm >> i) & 1;
                float sj[4];
                #pragma unroll
                for (int j = 0; j < 4; ++j) {
                    float s = 0.f;
                    #pragma unroll
                    for (int r = 0; r < 4; ++r) s += fmaxf(acc[i][j][r] + bias[j], 0.f);
                    s += __shfl_down(s, 32, 64);
                    s += __shfl_down(s, 16, 64);
                    sj[j] = s;                      // full sum valid on lanes 0..15
                }
                // redistribute: lane L holds row value for column wn + L
                float v0 = __shfl(sj[0], ml, 64);
                float v1 = __shfl(sj[1], ml, 64);
                float v2 = __shfl(sj[2], ml, 64);
                float v3 = __shfl(sj[3], ml, 64);
                float vv = (q == 0) ? v0 : (q == 1) ? v1 : (q == 2) ? v2 : v3;
                float val = vv * inv;
                float* dst = &wemb[(size_t)(bW + w0) * H_ + h0 + wn + lane];
                if (own) *dst = val;                // 64 lanes: 256B coalesced
                else atomicAdd(dst, val);
            }
        } else {
            #pragma unroll
            for (int j = 0; j < 4; ++j) {
                #pragma unroll
                for (int r = 0; r < 4; ++r) {
                    int t = tg + q * 4 + r;
                    int w = word_of[bT + t];
                    if (w >= 0)
                        atomicAdd(&wemb[(size_t)(bW + w) * H_ + h0 + wn + j * 16 + ml],
                                  fmaxf(acc[i][j][r] + bias[j], 0.f) * inv_cnt[bW + w]);
                }
            }
        }
    }
}

// ---------------------------------------------------------------------------
// Decoder: 512 blocks (b x 16 chunks of 8 words) for latency-hiding
// ---------------------------------------------------------------------------
__global__ __launch_bounds__(256) void dec_all(const float* __restrict__ wemb,
                                               const float* __restrict__ dec_w,
                                               const float* __restrict__ dec_b,
                                               float* __restrict__ out) {
    __shared__ float sdw[H_ * K_];       // 10.2 KB
    __shared__ float se[16][8];          // 12 rows used, k-stride 8
    const int bid = blockIdx.x;          // b*16 + ch
    const int b = bid >> 4, ch = bid & 15;
    const int w0 = ch * 8;
    for (int idx = threadIdx.x; idx < H_ * K_; idx += 256) sdw[idx] = dec_w[idx];
    __syncthreads();
    const int wid = threadIdx.x >> 6, lane = threadIdx.x & 63;
    for (int row = wid; row < 12; row += 4) {
        int wq = w0 - 2 + row;
        float a[K_] = {};
        if (wq >= 0 && wq < W_) {
            const float* src = wemb + ((size_t)b * W_ + wq) * H_;
            #pragma unroll
            for (int r = 0; r < H_ / 64; ++r) {
                int h = r * 64 + lane;
                float v = src[h];
                #pragma unroll
                for (int k = 0; k < K_; ++k) a[k] += v * sdw[h * K_ + k];
            }
        }
        #pragma unroll
        for (int k = 0; k < K_; ++k) {
            #pragma unroll
            for (int off = 32; off > 0; off >>= 1) a[k] += __shfl_down(a[k], off, 64);
        }
        if (lane == 0) {
            #pragma unroll
            for (int k = 0; k < K_; ++k) se[row][k] = a[k];
        }
    }
    __syncthreads();
    if (threadIdx.x < 8) {
        int wl = threadIdx.x;
        float acc = dec_b[0];
        #pragma unroll
        for (int k = 0; k < K_; ++k) acc += se[wl + k][k];
        out[b * W_ + w0 + wl] = acc;
    }
}

// ---------------------------------------------------------------------------
extern "C" void kernel_launch(void* const* d_in, const int* in_sizes, int n_in,
                              void* d_out, int out_size, void* d_ws, size_t ws_size,
                              hipStream_t stream) {
    const float* feat    = (const float*)d_in[0];
    const int*   bounds  = (const int*)  d_in[1];
    const int*   lengths = (const int*)  d_in[2];
    const float* enc_w   = (const float*)d_in[3];
    const float* enc_b   = (const float*)d_in[4];
    const float* dec_w   = (const float*)d_in[5];
    const float* dec_b   = (const float*)d_in[6];
    float* out = (float*)d_out;

    char* p = (char*)d_ws;
    _Float16* featT = (_Float16*)p;  p += (size_t)B_ * T_ * C_ * 2;                 // 10.49 MB
    _Float16* Bf    = (_Float16*)p;  p += (size_t)(BF_ELEMS + 4 * ITER_STRIDE) * 2; // 0.44 MB (+4-iter pad)
    int* word_of    = (int*)p;       p += (size_t)B_ * T_ * 4;                      // 0.26 MB
    float* inv_cnt  = (float*)p;     p += (size_t)B_ * W_ * 4;                      // 16 KB
    float* wemb     = (float*)p;                                                    // 8.39 MB (no pre-zero needed)

    prep_all<<<RB_WORDS, 256, 0, stream>>>(feat, enc_w, bounds, lengths,
                                           featT, Bf, word_of, inv_cnt);
    gemm_enc<<<B_ * (T_ / TM) * (H_ / TN), 256, 0, stream>>>(
        featT, Bf, enc_b, word_of, inv_cnt, wemb);
    dec_all<<<B_ * 16, 256, 0, stream>>>(wemb, dec_w, dec_b, out);
}